// Round 5
// baseline (856.650 us; speedup 1.0000x reference)
//
#include <hip/hip_runtime.h>
#include <hip/hip_bf16.h>

// ============================================================================
// RecurrentDecoder v14: 160-block persistent kernel, flag dataflow.
// v13 -> v14:
//  - ctx phase via MFMA: ctx[f] = sum_t a[f,t]*tw[t] as 16 m-tiles x K=256
//    with B = tw replicated across n (all D columns equal). tw split hi+lo
//    bf16 (double-bf16 ~ fp32 precision) -> 32 MFMA/wave. Deletes the
//    cp[2][256] VALU reduce (~256 FMA/thread) and one barrier (7->6/step).
//    alds pad 260->264 keeps ds_read_b128 A-frags 16B-aligned, 2-way banks.
//  - mel folded into GRU blocks 0..5 waves 6-7 (idle during MFMA phase):
//    at GRU step s, hA=h(s) and cA still holds ctx(s-1) -> mel(s-1) computed
//    during the ctxdone wait. Epilogue computes mel(63) after the loop.
//    Deletes mel blocks (162->160 blocks) and ALL meldone flag machinery.
//    Ring-4 + hdone ordering still protects ctxb slots.
//  - waitge tight-spins (no s_sleep): poll period is RT-bound anyway.
// Everything else as v13: 4-way e-split att (128 blocks), block-local
// softmax, partial-ctx quarters, GRU K=1024 with WC[kt&7], GRU 128..159.
// ============================================================================

#define LOG2E 1.4426950408889634f
#define FLAGS_MAGIC 0x13572468u
#define SMEM_BYTES 139776
#define NBLK 160

typedef __attribute__((ext_vector_type(8))) short bf8;
typedef __attribute__((ext_vector_type(4))) float f32x4;
typedef __attribute__((ext_vector_type(4))) unsigned u32x4;
typedef unsigned long long ull;

#define EX2(x) exp2f(x)
#define MFMA16(a, b, c) __builtin_amdgcn_mfma_f32_16x16x32_bf16(a, b, c, 0, 0, 0)

struct Params {
  const float* dec;
  const float* ali;
  const float* watt;
  const float* wih;
  const float* whh;
  const float* wmel;
  const float* bmel;
  const float* wgate;
  const float* bgate;
  float* out;
  unsigned* bar;  // [0]=magic [16]=p0cnt [32+16i]=hdone(32) [544+16j]=ctxdone(128)
  __hip_bfloat16* wihb;    // [1536][512]
  __hip_bfloat16* whhb;    // [1536][512]
  __hip_bfloat16* wmelgb;  // [96][768]
  __hip_bfloat16* seqb;    // [64][32][256]
  __hip_bfloat16* hbf;     // ring [4][32][512]
  __hip_bfloat16* ctxb;    // ring [4][128][256]  (hb = q4*32+b, partial quarters)
  unsigned* wattp;         // [256][256] packed bf16 pairs of W_att^T
};

__device__ __forceinline__ bf8 ldfrag(const __hip_bfloat16* p) { return *(const bf8*)p; }
__device__ __forceinline__ float sigm(float x) { return 1.0f / (1.0f + EX2(-x * LOG2E)); }
__device__ __forceinline__ float tanhfast(float x) {
  x = fminf(fmaxf(x, -15.0f), 15.0f);
  float e = EX2(x * (2.0f * LOG2E));
  return (e - 1.0f) / (e + 1.0f);
}
__device__ __forceinline__ float btof(unsigned v) { return __uint_as_float(v << 16); }
__device__ __forceinline__ unsigned short f2bfbits(float x) {
  __hip_bfloat16 h = __float2bfloat16(x);
  return *(unsigned short*)&h;
}
__device__ __forceinline__ unsigned sysld32(const unsigned* p) {
  return __hip_atomic_load(p, __ATOMIC_RELAXED, __HIP_MEMORY_SCOPE_SYSTEM);
}
__device__ __forceinline__ ull sysld64(const ull* p) {
  return __hip_atomic_load(p, __ATOMIC_RELAXED, __HIP_MEMORY_SCOPE_SYSTEM);
}
__device__ __forceinline__ void sysst32(unsigned* p, unsigned v) {
  __hip_atomic_store(p, v, __ATOMIC_RELAXED, __HIP_MEMORY_SCOPE_SYSTEM);
}
__device__ __forceinline__ void sysst64(ull* p, ull v) {
  __hip_atomic_store(p, v, __ATOMIC_RELAXED, __HIP_MEMORY_SCOPE_SYSTEM);
}
__device__ __forceinline__ void sysld16x4(u32x4* d0, u32x4* d1, u32x4* d2, u32x4* d3,
                                          const void* p0, const void* p1,
                                          const void* p2, const void* p3) {
  u32x4 a, b, c, d;
  asm volatile(
      "global_load_dwordx4 %0, %4, off sc0 sc1\n\t"
      "global_load_dwordx4 %1, %5, off sc0 sc1\n\t"
      "global_load_dwordx4 %2, %6, off sc0 sc1\n\t"
      "global_load_dwordx4 %3, %7, off sc0 sc1\n\t"
      "s_waitcnt vmcnt(0)"
      : "=&v"(a), "=&v"(b), "=&v"(c), "=&v"(d)
      : "v"(p0), "v"(p1), "v"(p2), "v"(p3)
      : "memory");
  *d0 = a; *d1 = b; *d2 = c; *d3 = d;
}
// 8 coherent dwordx4 loads, ONE vmcnt(0): single round-trip staging.
__device__ __forceinline__ void sysld16x8(u32x4* d0, u32x4* d1, u32x4* d2, u32x4* d3,
                                          u32x4* d4, u32x4* d5, u32x4* d6, u32x4* d7,
                                          const void* p0, const void* p1,
                                          const void* p2, const void* p3,
                                          const void* p4, const void* p5,
                                          const void* p6, const void* p7) {
  u32x4 a, b, c, d, e, f, g, h;
  asm volatile(
      "global_load_dwordx4 %0, %8, off sc0 sc1\n\t"
      "global_load_dwordx4 %1, %9, off sc0 sc1\n\t"
      "global_load_dwordx4 %2, %10, off sc0 sc1\n\t"
      "global_load_dwordx4 %3, %11, off sc0 sc1\n\t"
      "global_load_dwordx4 %4, %12, off sc0 sc1\n\t"
      "global_load_dwordx4 %5, %13, off sc0 sc1\n\t"
      "global_load_dwordx4 %6, %14, off sc0 sc1\n\t"
      "global_load_dwordx4 %7, %15, off sc0 sc1\n\t"
      "s_waitcnt vmcnt(0)"
      : "=&v"(a), "=&v"(b), "=&v"(c), "=&v"(d),
        "=&v"(e), "=&v"(f), "=&v"(g), "=&v"(h)
      : "v"(p0), "v"(p1), "v"(p2), "v"(p3),
        "v"(p4), "v"(p5), "v"(p6), "v"(p7)
      : "memory");
  *d0 = a; *d1 = b; *d2 = c; *d3 = d;
  *d4 = e; *d5 = f; *d6 = g; *d7 = h;
}
__device__ __forceinline__ void waitge(unsigned* w, unsigned tgt) {
  while (sysld32(w) < tgt) {}
}

__device__ __forceinline__ void p0bar(unsigned* bar) {
  __syncthreads();
  if (threadIdx.x == 0) {
    __builtin_amdgcn_fence(__ATOMIC_RELEASE, "agent");
    __hip_atomic_fetch_add(bar + 16, 1u, __ATOMIC_RELAXED, __HIP_MEMORY_SCOPE_SYSTEM);
    while (sysld32(bar + 16) < (unsigned)NBLK) __builtin_amdgcn_s_sleep(1);
    __builtin_amdgcn_fence(__ATOMIC_ACQUIRE, "agent");
  }
  __syncthreads();
}

// P0 conversion work for blocks 128..159 (wid in [0, 32*512))
__device__ __forceinline__ void p0a_worker(const Params& p, int wid) {
  for (int i = wid; i < 2252800; i += 16384) {
    if (i < 786432) {
      p.wihb[i] = __float2bfloat16(p.wih[i]);
    } else if (i < 1572864) {
      int j = i - 786432;
      p.whhb[j] = __float2bfloat16(p.whh[j]);
    } else if (i < 2097152) {
      int j = i - 1572864;
      int s = j >> 13;
      p.seqb[j] = (s == 0) ? __float2bfloat16(0.0f) : __float2bfloat16(p.dec[j - 8192]);
    } else if (i < 2170880) {
      int j = i - 2097152;
      int r = j / 768, c = j - r * 768;
      float v = (r < 80) ? p.wmel[j] : ((r == 80) ? p.wgate[c] : 0.0f);
      p.wmelgb[j] = __float2bfloat16(v);
    } else if (i < 2236416) {
      int j = i - 2170880;
      int kp = j >> 8, e = j & 255;
      unsigned lo = f2bfbits(p.watt[e * 512 + 2 * kp]);
      unsigned hi = f2bfbits(p.watt[e * 512 + 2 * kp + 1]);
      p.wattp[j] = lo | (hi << 16);
    } else {
      int j = i - 2236416;
      p.hbf[j] = __float2bfloat16(0.0f);  // h ring slot 0 = h(0) = 0
    }
  }
}

// Stage h[32][512] (row-major, coherent) into fragment-major LDS (32 sections).
__device__ __forceinline__ void stage_h_frag(__hip_bfloat16* hA,
                                             const __hip_bfloat16* hsrc, int tid) {
  const int lm = tid & 15, lq = (tid >> 4) & 3, wq = tid >> 6;
  const int dst_in = (lq * 16 + lm) * 8;
  const int i0 = wq, i1 = 8 + wq, i2 = 16 + wq, i3 = 24 + wq;
  auto soff = [&](int idx) {
    return ((idx >> 4) * 16 + lm) * 512 + (idx & 15) * 32 + lq * 8;
  };
  u32x4 a, b, c, d;
  sysld16x4(&a, &b, &c, &d, hsrc + soff(i0), hsrc + soff(i1), hsrc + soff(i2),
            hsrc + soff(i3));
  u32x4* dst = (u32x4*)hA;
  dst[(i0 * 512 + dst_in) >> 3] = a;
  dst[(i1 * 512 + dst_in) >> 3] = b;
  dst[(i2 * 512 + dst_in) >> 3] = c;
  dst[(i3 * 512 + dst_in) >> 3] = d;
}
// Stage concat-ctx [b, k=q4*256+e] (src ctxb slot: [128][256], hb=q4*32+b) into
// fragment-major LDS (64 sections over K=1024). Single coherent round-trip.
__device__ __forceinline__ void stage_c4(__hip_bfloat16* cA,
                                         const __hip_bfloat16* csrc, int tid) {
  const int lm = tid & 15, lq = (tid >> 4) & 3, wq = tid >> 6;
  const int dst_in = (lq * 16 + lm) * 8;
  u32x4* dst = (u32x4*)cA;
  auto soff = [&](int idx) {
    int mt = idx >> 5, kt = idx & 31;
    int bb = mt * 16 + lm;
    int k = kt * 32 + lq * 8;
    return ((k >> 8) * 32 + bb) * 256 + (k & 255);
  };
  const int i0 = wq, i1 = 8 + wq, i2 = 16 + wq, i3 = 24 + wq;
  const int i4 = 32 + wq, i5 = 40 + wq, i6 = 48 + wq, i7 = 56 + wq;
  u32x4 a, b, c, d, e, f, g, h;
  sysld16x8(&a, &b, &c, &d, &e, &f, &g, &h,
            csrc + soff(i0), csrc + soff(i1), csrc + soff(i2), csrc + soff(i3),
            csrc + soff(i4), csrc + soff(i5), csrc + soff(i6), csrc + soff(i7));
  dst[(i0 * 512 + dst_in) >> 3] = a;
  dst[(i1 * 512 + dst_in) >> 3] = b;
  dst[(i2 * 512 + dst_in) >> 3] = c;
  dst[(i3 * 512 + dst_in) >> 3] = d;
  dst[(i4 * 512 + dst_in) >> 3] = e;
  dst[(i5 * 512 + dst_in) >> 3] = f;
  dst[(i6 * 512 + dst_in) >> 3] = g;
  dst[(i7 * 512 + dst_in) >> 3] = h;
}

__global__ void __launch_bounds__(512, 1) rdec_kernel(Params p) {
  const int tid = threadIdx.x;
  const int bid = blockIdx.x;
  extern __shared__ char smem[];
  unsigned* hdone = p.bar + 32;     // 32 flags
  unsigned* ctxdone = p.bar + 544;  // 128 flags

  if (bid == 0) {
    for (int i = 1 + tid; i < 2624; i += 512) sysst32(p.bar + i, 0u);
    __syncthreads();
    if (tid == 0) sysst32(p.bar, FLAGS_MAGIC);
  }

  if (bid < 128) {
    // =================== ATT path (batch b, e-quarter q4) ===================
    const int b = bid >> 2, q4 = bid & 3, hb = q4 * 32 + b;
    unsigned short* alds = (unsigned short*)smem;  // [256 f][264 t] bf16 (pad)
    float* fb = (float*)(smem + 135168);
    float* shh = fb;          // 512   h(s)[b,:]
    float* p2l = fb + 512;    // 64    proj_e * LOG2E (my e-quarter)
    float* rzl = fb + 576;    // 64    1/Z_e
    float* ctxf = fb + 640;   // 256   ctx partial (fp32, from MFMA)
    unsigned short* twb = (unsigned short*)(fb + 896);  // [512] tw hi|lo bf16

    // el in lane LOW bits (bank spread), kq in lane bits 3..5 (shfl 8/16/32)
    const int el = (tid & 7) | ((tid >> 6) << 3);  // e-local / t-quad (0..63)
    const int kq = (tid >> 3) & 7;                 // k-/t-eighth / e-group
    const int w = tid >> 6, l = tid & 63;          // MFMA mapping
    const int lm = l & 15, lq = l >> 4;

    // P0: full a[:,b,:] -> alds[f][t]
    for (int i = tid; i < 65536; i += 512) {
      int t = i >> 8, ee = i & 255;
      alds[ee * 264 + t] = f2bfbits(p.ali[t * 8192 + b * 256 + ee]);
    }
    if (tid == 0) {
      while (sysld32(p.bar) != FLAGS_MAGIC) __builtin_amdgcn_s_sleep(1);
    }
    p0bar(p.bar);
    // k-strided weight regs: kp = i*8 + kq
    unsigned wr[32];
#pragma unroll
    for (int i = 0; i < 32; ++i) wr[i] = p.wattp[(i * 8 + kq) * 256 + q4 * 64 + el];

    for (int s = 0; s < 64; ++s) {
      if (tid < 32) waitge(hdone + tid * 16, (unsigned)s);
      __syncthreads();
      // h(s)[b,:] -> shh fp32
      if (tid < 128) {
        ull wv = sysld64((const ull*)(p.hbf + (s & 3) * 16384 + b * 512) + tid);
        shh[tid * 4 + 0] = btof((unsigned)(wv & 0xffff));
        shh[tid * 4 + 1] = btof((unsigned)((wv >> 16) & 0xffff));
        shh[tid * 4 + 2] = btof((unsigned)((wv >> 32) & 0xffff));
        shh[tid * 4 + 3] = btof((unsigned)((wv >> 48) & 0xffff));
      }
      __syncthreads();
      // proj (k-eighth) + Z (t-eighth) fused in-register, shfl 8/16/32
      {
        const float2* h2 = (const float2*)shh;
        float a0 = 0.f, a1 = 0.f;
#pragma unroll
        for (int i = 0; i < 32; i += 2) {
          unsigned w0 = wr[i], w1 = wr[i + 1];
          float2 h0 = h2[i * 8 + kq], h1 = h2[(i + 1) * 8 + kq];
          a0 = fmaf(__uint_as_float(w0 << 16), h0.x, a0);
          a0 = fmaf(__uint_as_float(w0 & 0xffff0000u), h0.y, a0);
          a1 = fmaf(__uint_as_float(w1 << 16), h1.x, a1);
          a1 = fmaf(__uint_as_float(w1 & 0xffff0000u), h1.y, a1);
        }
        float pr = a0 + a1;
        pr += __shfl_xor(pr, 8);
        pr += __shfl_xor(pr, 16);
        pr += __shfl_xor(pr, 32);
        const float pp = pr * LOG2E;
        // Z partial over my t-eighth (32 t)
        const unsigned short* ap = alds + (q4 * 64 + el) * 264 + kq * 32;
        float z0 = 0.f, z1 = 0.f;
#pragma unroll
        for (int j = 0; j < 8; ++j) {
          ushort4 v = *(const ushort4*)(ap + j * 4);
          z0 += EX2(btof(v.x) * pp) + EX2(btof(v.y) * pp);
          z1 += EX2(btof(v.z) * pp) + EX2(btof(v.w) * pp);
        }
        float zz = z0 + z1;
        zz += __shfl_xor(zz, 8);
        zz += __shfl_xor(zz, 16);
        zz += __shfl_xor(zz, 32);
        if (kq == 0) {
          p2l[el] = pp;
          rzl[el] = 1.0f / zz;
        }
      }
      __syncthreads();
      // pass2: tw_t = sum_e u/Z over my 64 e; shfl 8/16/32 over e-groups.
      // Writers pack tw as hi+lo bf16 directly into twb (double-bf16).
      {
        float t0 = 0.f, t1 = 0.f, t2 = 0.f, t3 = 0.f;
#pragma unroll
        for (int j = 0; j < 8; ++j) {
          const int e2 = kq * 8 + j;
          ushort4 v = *(const ushort4*)(alds + (q4 * 64 + e2) * 264 + el * 4);
          const float ppj = p2l[e2], rr = rzl[e2];
          t0 = fmaf(EX2(btof(v.x) * ppj), rr, t0);
          t1 = fmaf(EX2(btof(v.y) * ppj), rr, t1);
          t2 = fmaf(EX2(btof(v.z) * ppj), rr, t2);
          t3 = fmaf(EX2(btof(v.w) * ppj), rr, t3);
        }
        t0 += __shfl_xor(t0, 8); t0 += __shfl_xor(t0, 16); t0 += __shfl_xor(t0, 32);
        t1 += __shfl_xor(t1, 8); t1 += __shfl_xor(t1, 16); t1 += __shfl_xor(t1, 32);
        t2 += __shfl_xor(t2, 8); t2 += __shfl_xor(t2, 16); t2 += __shfl_xor(t2, 32);
        t3 += __shfl_xor(t3, 8); t3 += __shfl_xor(t3, 16); t3 += __shfl_xor(t3, 32);
        if (kq == 0) {
          unsigned short h0 = f2bfbits(t0), h1 = f2bfbits(t1);
          unsigned short h2c = f2bfbits(t2), h3 = f2bfbits(t3);
          unsigned short l0 = f2bfbits(t0 - btof(h0)), l1 = f2bfbits(t1 - btof(h1));
          unsigned short l2 = f2bfbits(t2 - btof(h2c)), l3 = f2bfbits(t3 - btof(h3));
          *(ull*)(twb + el * 4) =
              (ull)h0 | ((ull)h1 << 16) | ((ull)h2c << 32) | ((ull)h3 << 48);
          *(ull*)(twb + 256 + el * 4) =
              (ull)l0 | ((ull)l1 << 16) | ((ull)l2 << 32) | ((ull)l3 << 48);
        }
      }
      __syncthreads();
      // ctx via MFMA: D[m-tile][n] = A(a[f][t]) x B(tw[t] replicated over n).
      // 16 m-tiles, K=256 x {hi,lo} -> 32 MFMA/wave; lane lm==0 extracts.
      {
        bf8 tb[16];
#pragma unroll
        for (int kt = 0; kt < 16; ++kt)
          tb[kt] = *(const bf8*)(twb + (kt >> 3) * 256 + (kt & 7) * 32 + lq * 8);
#pragma unroll
        for (int half = 0; half < 2; ++half) {
          const int mt = w * 2 + half;
          bf8 af[8];
#pragma unroll
          for (int kt = 0; kt < 8; ++kt)
            af[kt] = *(const bf8*)(alds + (mt * 16 + lm) * 264 + kt * 32 + lq * 8);
          f32x4 acc = {0.f, 0.f, 0.f, 0.f};
#pragma unroll
          for (int kt = 0; kt < 16; ++kt) acc = MFMA16(af[kt & 7], tb[kt], acc);
          if (lm == 0) {
#pragma unroll
            for (int r = 0; r < 4; ++r) ctxf[mt * 16 + lq * 4 + r] = acc[r];
          }
        }
      }
      __syncthreads();
      // pack + publish (128 threads, 2 f each)
      if (tid < 128) {
        float cv0 = ctxf[2 * tid], cv1 = ctxf[2 * tid + 1];
        unsigned u = (unsigned)f2bfbits(cv0) | ((unsigned)f2bfbits(cv1) << 16);
        sysst32((unsigned*)(p.ctxb + ((s & 3) * 128 + hb) * 256) + tid, u);
      }
      __syncthreads();
      if (tid == 0) sysst32(ctxdone + hb * 16, (unsigned)(s + 1));
    }
  } else {
    // ==================== GRU path (+ folded mel on blocks 0..5) ====================
    const int dt = bid - 128;
    const int wv = tid >> 6;
    const bool act = wv < 6;
    const int l = tid & 63, lm = l & 15, lq = l >> 4;
    const int g = wv % 3, mt = wv / 3;
    const int am = mt * 16 + lm;
    const int brow = g * 512 + dt * 16 + lm;
    __hip_bfloat16* hA = (__hip_bfloat16*)smem;             // frag-major 32KB
    __hip_bfloat16* cA = (__hip_bfloat16*)(smem + 32768);   // frag-major 64KB (K=1024)
    float* pw = (float*)(smem + 98304);                     // [8][16][17]
    unsigned short* h16 = (unsigned short*)(smem + 107008); // [512]
    p0a_worker(p, (bid - 128) * 512 + tid);
    if (tid == 0) {
      while (sysld32(p.bar) != FLAGS_MAGIC) __builtin_amdgcn_s_sleep(1);
    }
    p0bar(p.bar);
    bf8 WH[16], WD[8], WC[8];
    if (act) {
#pragma unroll
      for (int kt = 0; kt < 16; ++kt) WH[kt] = ldfrag(p.whhb + brow * 512 + kt * 32 + lq * 8);
#pragma unroll
      for (int kt = 0; kt < 8; ++kt) WD[kt] = ldfrag(p.wihb + brow * 512 + kt * 32 + lq * 8);
#pragma unroll
      for (int kt = 0; kt < 8; ++kt) WC[kt] = ldfrag(p.wihb + brow * 512 + 256 + kt * 32 + lq * 8);
    }
    // folded mel: blocks 0..5, waves 6-7. nt = dt, mmt = wv-6 (batch half).
    const bool melw = (dt < 6) && (wv >= 6);
    bf8 WMC[8], WMH[16];
    float mbias = 0.f;
    int mmt = 0, bn = 0;
    if (melw) {
      mmt = wv - 6;
      bn = dt * 16 + lm;
#pragma unroll
      for (int kt = 0; kt < 8; ++kt) WMC[kt] = ldfrag(p.wmelgb + bn * 768 + kt * 32 + lq * 8);
#pragma unroll
      for (int kt = 0; kt < 16; ++kt)
        WMH[kt] = ldfrag(p.wmelgb + bn * 768 + 256 + kt * 32 + lq * 8);
      mbias = (bn < 80) ? p.bmel[bn] : ((bn == 80) ? p.bgate[0] : 0.f);
    }
    for (int s = 0; s < 64; ++s) {
      if (tid < 32) waitge(hdone + tid * 16, (unsigned)s);
      __syncthreads();
      stage_h_frag(hA, p.hbf + (s & 3) * 16384, tid);
      __syncthreads();
      f32x4 acc = {0.f, 0.f, 0.f, 0.f};
      f32x4 gi = {0.f, 0.f, 0.f, 0.f};
      if (act) {
#pragma unroll
        for (int kt = 0; kt < 16; ++kt) {
          bf8 a = ldfrag(hA + (mt * 16 + kt) * 512 + l * 8);
          acc = MFMA16(a, WH[kt], acc);
        }
        const __hip_bfloat16* seqp = p.seqb + s * 8192;
#pragma unroll
        for (int kt = 0; kt < 8; ++kt) {
          bf8 a = ldfrag(seqp + am * 256 + kt * 32 + lq * 8);
          gi = MFMA16(a, WD[kt], gi);
        }
      } else if (melw && s > 0) {
        // mel(s-1): cA still holds ctx(s-1); hA = h(s) = h_new(s-1).
        const int tau = s - 1;
        f32x4 macc = {0.f, 0.f, 0.f, 0.f};
#pragma unroll
        for (int kt = 0; kt < 48; ++kt) {
          bf8 a = (kt < 32) ? ldfrag(cA + (mmt * 32 + kt) * 512 + l * 8)
                            : ldfrag(hA + (mmt * 16 + (kt - 32)) * 512 + l * 8);
          bf8 bb2 = (kt < 32) ? WMC[kt & 7] : WMH[kt - 32];
          macc = MFMA16(a, bb2, macc);
        }
#pragma unroll
        for (int r = 0; r < 4; ++r) {
          int bb = mmt * 16 + lq * 4 + r;
          float v = macc[r] + mbias;
          if (bn < 80)
            p.out[bb * 5120 + bn * 64 + tau] = v;
          else if (bn == 80)
            p.out[163840 + bb * 64 + tau] = v;
        }
      }
      if (tid < 128) waitge(ctxdone + tid * 16, (unsigned)(s + 1));
      __syncthreads();
      stage_c4(cA, p.ctxb + (s & 3) * 32768, tid);
      __syncthreads();
      if (act) {
        // gi_ctx over K=1024 concat quarters with duplicated W rows
#pragma unroll
        for (int kt = 0; kt < 32; ++kt) {
          bf8 a = ldfrag(cA + (mt * 32 + kt) * 512 + l * 8);
          gi = MFMA16(a, WC[kt & 7], gi);
        }
        if (g < 2) {
#pragma unroll
          for (int r = 0; r < 4; ++r) pw[(wv * 16 + lq * 4 + r) * 17 + lm] = acc[r] + gi[r];
        } else {
#pragma unroll
          for (int r = 0; r < 4; ++r) pw[(wv * 16 + lq * 4 + r) * 17 + lm] = acc[r];
#pragma unroll
          for (int r = 0; r < 4; ++r) pw[((6 + mt) * 16 + lq * 4 + r) * 17 + lm] = gi[r];
        }
      }
      __syncthreads();
      {
        const int bb = tid >> 4, dl = tid & 15;
        const int mtb = bb >> 4, bl = bb & 15;
        float rg = sigm(pw[((mtb * 3 + 0) * 16 + bl) * 17 + dl]);
        float zg = sigm(pw[((mtb * 3 + 1) * 16 + bl) * 17 + dl]);
        float hn = pw[((mtb * 3 + 2) * 16 + bl) * 17 + dl];
        float inn = pw[((6 + mtb) * 16 + bl) * 17 + dl];
        float nn = tanhfast(fmaf(rg, hn, inn));
        const int d = dt * 16 + dl;
        float ho = btof(((unsigned short*)hA)[((bb >> 4) * 16 + (d >> 5)) * 512 +
                                              (((d >> 3) & 3) * 16 + (bb & 15)) * 8 +
                                              (d & 7)]);
        float hnew = fmaxf(0.0f, fmaf(zg, ho - nn, nn));
        h16[bb * 16 + dl] = f2bfbits(hnew);
      }
      __syncthreads();
      if (tid < 256) {
        const int bb2 = tid >> 3, dp = tid & 7;
        unsigned v = (unsigned)h16[bb2 * 16 + dp * 2] |
                     ((unsigned)h16[bb2 * 16 + dp * 2 + 1] << 16);
        sysst32((unsigned*)(p.hbf + ((s + 1) & 3) * 16384) + bb2 * 256 + dt * 8 + dp, v);
      }
      __syncthreads();
      if (tid == 0) sysst32(hdone + dt * 16, (unsigned)(s + 1));
    }
    // Epilogue: mel(63) needs h(64) (hbf slot 0) and ctx(63) (still in cA).
    if (dt < 6) {
      if (tid < 32) waitge(hdone + tid * 16, 64u);
      __syncthreads();
      stage_h_frag(hA, p.hbf + 0, tid);
      __syncthreads();
      if (melw) {
        f32x4 macc = {0.f, 0.f, 0.f, 0.f};
#pragma unroll
        for (int kt = 0; kt < 48; ++kt) {
          bf8 a = (kt < 32) ? ldfrag(cA + (mmt * 32 + kt) * 512 + l * 8)
                            : ldfrag(hA + (mmt * 16 + (kt - 32)) * 512 + l * 8);
          bf8 bb2 = (kt < 32) ? WMC[kt & 7] : WMH[kt - 32];
          macc = MFMA16(a, bb2, macc);
        }
#pragma unroll
        for (int r = 0; r < 4; ++r) {
          int bb = mmt * 16 + lq * 4 + r;
          float v = macc[r] + mbias;
          if (bn < 80)
            p.out[bb * 5120 + bn * 64 + 63] = v;
          else if (bn == 80)
            p.out[163840 + bb * 64 + 63] = v;
        }
      }
    }
  }
}

extern "C" void kernel_launch(void* const* d_in, const int* in_sizes, int n_in,
                              void* d_out, int out_size, void* d_ws, size_t ws_size,
                              hipStream_t stream) {
  Params P;
  P.dec = (const float*)d_in[0];
  P.ali = (const float*)d_in[1];
  P.watt = (const float*)d_in[2];
  P.wih = (const float*)d_in[3];
  P.whh = (const float*)d_in[4];
  P.wmel = (const float*)d_in[5];
  P.bmel = (const float*)d_in[6];
  P.wgate = (const float*)d_in[7];
  P.bgate = (const float*)d_in[8];
  P.out = (float*)d_out;

  char* w = (char*)d_ws;
  size_t o = 0;
  auto nxt = [&](size_t b) {
    char* r = w + o;
    o += (b + 255) & ~(size_t)255;
    return r;
  };
  P.bar = (unsigned*)nxt(16384);
  P.wihb = (__hip_bfloat16*)nxt(1536 * 512 * 2);
  P.whhb = (__hip_bfloat16*)nxt(1536 * 512 * 2);
  P.wmelgb = (__hip_bfloat16*)nxt(96 * 768 * 2);
  P.seqb = (__hip_bfloat16*)nxt(64 * 32 * 256 * 2);
  P.hbf = (__hip_bfloat16*)nxt(4 * 32 * 512 * 2);
  P.ctxb = (__hip_bfloat16*)nxt(4 * 128 * 256 * 2);
  P.wattp = (unsigned*)nxt(256 * 256 * 4);

  (void)hipFuncSetAttribute((const void*)rdec_kernel,
                            hipFuncAttributeMaxDynamicSharedMemorySize, SMEM_BYTES);

  void* args[] = {&P};
  hipError_t err = hipLaunchCooperativeKernel((void*)rdec_kernel, dim3(NBLK), dim3(512),
                                              args, SMEM_BYTES, stream);
  if (err != hipSuccess) {
    rdec_kernel<<<dim3(NBLK), dim3(512), SMEM_BYTES, stream>>>(P);
  }
}